// Round 6
// baseline (130.381 us; speedup 1.0000x reference)
//
#include <hip/hip_runtime.h>

#define NB 8
#define NC 19
#define HW (512*512)
#define NPIX (NB*HW)
#define RANK 183500u   // max(100000, int(262144*0.7)), < n_pix-1
#define NBIN 4096
#define CAPL 4096      // LDS candidate capacity in select_kernel

__device__ __forceinline__ unsigned fkey(float f) {
    unsigned b = __float_as_uint(f);
    return (b & 0x80000000u) ? ~b : (b | 0x80000000u);
}
__device__ __forceinline__ float finv(unsigned u) {
    unsigned b = (u & 0x80000000u) ? (u & 0x7fffffffu) : ~u;
    return __uint_as_float(b);
}
__device__ __forceinline__ int bin_of(float l) {
    int b = (int)((l + 1.0f) * 224.0f);
    return b < 0 ? 0 : (b > NBIN - 1 ? NBIN - 1 : b);
}
__device__ __forceinline__ unsigned umn(unsigned a, unsigned b) { return a < b ? a : b; }
__device__ __forceinline__ unsigned umx(unsigned a, unsigned b) { return a > b ? a : b; }

// ---------------- Kernel 1: CE losses, 2 px/thread (float2), max TLP --------
// Block-uniform batch => channel bases in SGPRs. 19 float2 loads in flight per
// thread. Per-pixel FP sequence bit-identical to rounds 1-5 (absmax=0 pedigree).
// Side duties: blocks 0..31 zero ghist; per-block presence atomicOr.
__global__ __launch_bounds__(256) void losses_kernel(
    const float* __restrict__ logits, const int* __restrict__ targets,
    float* __restrict__ losses, unsigned* __restrict__ present,
    unsigned* __restrict__ ghist)
{
    __shared__ unsigned pres;
    const int blk  = blockIdx.x;
    const int pix0 = blk * 512;
    const int bb   = pix0 >> 18;          // batch (512 | HW, never straddles)
    const int pp   = pix0 & (HW - 1);
    const int tid  = threadIdx.x;

    if (tid == 0) pres = 0u;
    if (blk < 32)   // zero ghist (hist_kernel runs strictly after this kernel)
        for (int j = tid; j < 1024; j += 256) ghist[blk * 1024 + j] = 0u;

    const float* base = logits + (size_t)bb * NC * HW + pp + tid * 2;
    float2 x[NC];
    #pragma unroll
    for (int c = 0; c < NC; ++c)
        x[c] = *reinterpret_cast<const float2*>(base + (size_t)c * HW);

    int2 t = *reinterpret_cast<const int2*>(targets + pix0 + tid * 2);

    float m0 = x[0].x, m1 = x[0].y;
    #pragma unroll
    for (int c = 1; c < NC; ++c) { m0 = fmaxf(m0, x[c].x); m1 = fmaxf(m1, x[c].y); }

    float s0 = 0.f, s1 = 0.f, e0t = 0.f, e1t = 0.f;
    #pragma unroll
    for (int c = 0; c < NC; ++c) {
        float e0 = expf(x[c].x - m0); s0 += e0; if (c == t.x) e0t = e0;
        float e1 = expf(x[c].y - m1); s1 += e1; if (c == t.y) e1t = e1;
    }
    float o0 = 0.f, o1 = 0.f;
    unsigned mbit = 0u;
    if (t.x >= 0 && t.x < NC) { o0 = -logf(e0t / s0 + 1e-7f); mbit |= 1u << t.x; }
    if (t.y >= 0 && t.y < NC) { o1 = -logf(e1t / s1 + 1e-7f); mbit |= 1u << t.y; }
    *reinterpret_cast<float2*>(losses + pix0 + tid * 2) = make_float2(o0, o1);

    #pragma unroll
    for (int o = 1; o < 64; o <<= 1) mbit |= __shfl_xor(mbit, o);
    __syncthreads();   // pres=0 visible
    if ((tid & 63) == 0 && mbit) atomicOr(&pres, mbit);
    __syncthreads();
    if (tid == 0 && pres) atomicOr(&present[bb], pres);
}

// ---------------- Kernel 2: per-batch 4096-bin histogram ----------------
__global__ __launch_bounds__(256) void hist_kernel(
    const float* __restrict__ losses, unsigned* __restrict__ ghist)
{
    __shared__ unsigned lh[NBIN];
    const int b = blockIdx.y;
    for (int j = threadIdx.x; j < NBIN; j += 256) lh[j] = 0;
    __syncthreads();
    const float4* L = reinterpret_cast<const float4*>(losses + (size_t)b * HW)
                      + (size_t)blockIdx.x * 1024;
    for (int j = threadIdx.x; j < 1024; j += 256) {
        float4 v = L[j];
        atomicAdd(&lh[bin_of(v.x)], 1u);
        atomicAdd(&lh[bin_of(v.y)], 1u);
        atomicAdd(&lh[bin_of(v.z)], 1u);
        atomicAdd(&lh[bin_of(v.w)], 1u);
    }
    __syncthreads();
    unsigned* gh = ghist + b * NBIN;
    for (int j = threadIdx.x; j < NBIN; j += 256) {
        unsigned v = lh[j];
        if (v) atomicAdd(&gh[j], v);
    }
}

// ---------------- Kernel 3: fused pick+compact+final, fully parallel --------
// 1 block/batch, 1024 threads (16 waves). All rank-bin searches are block-
// parallel scans (no thread-0 serial LDS walks). Candidates live in LDS.
__global__ __launch_bounds__(1024) void select_kernel(
    const float* __restrict__ losses, const unsigned* __restrict__ ghist,
    float* __restrict__ thresh)
{
    __shared__ unsigned lh[NBIN];      // 16 KB
    __shared__ unsigned cand[CAPL];    // 16 KB
    __shared__ unsigned hsub[512];     // 2 KB
    __shared__ unsigned wsum[16], woff[16], redmin[16], redmax[16];
    __shared__ unsigned sh_bin, sh_r, sh_cnt, sh_kmin, sh_shift, sh_sb, sh_r2;

    const int b = blockIdx.x, tid = threadIdx.x;
    const int lane = tid & 63, wid = tid >> 6;

    for (int j = tid; j < NBIN; j += 1024) lh[j] = ghist[b * NBIN + j];
    if (tid == 0) sh_cnt = 0;
    __syncthreads();

    // ---- find rank bin over 4096 bins (4 bins/thread, block scan) ----
    unsigned s = lh[tid * 4] + lh[tid * 4 + 1] + lh[tid * 4 + 2] + lh[tid * 4 + 3];
    unsigned incl = s;
    #pragma unroll
    for (int o = 1; o < 64; o <<= 1) {
        unsigned v = (unsigned)__shfl_up((int)incl, o);
        if (lane >= o) incl += v;
    }
    if (lane == 63) wsum[wid] = incl;
    __syncthreads();
    if (tid == 0) { unsigned c = 0; for (int w = 0; w < 16; ++w) { woff[w] = c; c += wsum[w]; } }
    __syncthreads();
    unsigned excl = woff[wid] + incl - s;
    if (RANK >= excl && RANK < excl + s) {     // exactly one thread
        unsigned rr = RANK - excl, cum = 0;
        #pragma unroll
        for (int j = 0; j < 4; ++j) {
            unsigned c = lh[tid * 4 + j];
            if (cum + c > rr) { sh_bin = (unsigned)(tid * 4 + j); sh_r = rr - cum; break; }
            cum += c;
        }
    }
    __syncthreads();
    const int T = (int)sh_bin;
    const unsigned r = sh_r;

    // ---- gather candidates (bin == T) into LDS ----
    const float4* L = reinterpret_cast<const float4*>(losses + (size_t)b * HW);
    for (int j = tid; j < HW / 4; j += 1024) {
        float4 v = L[j];
        if (bin_of(v.x) == T) { unsigned i = atomicAdd(&sh_cnt, 1u); if (i < CAPL) cand[i] = fkey(v.x); }
        if (bin_of(v.y) == T) { unsigned i = atomicAdd(&sh_cnt, 1u); if (i < CAPL) cand[i] = fkey(v.y); }
        if (bin_of(v.z) == T) { unsigned i = atomicAdd(&sh_cnt, 1u); if (i < CAPL) cand[i] = fkey(v.z); }
        if (bin_of(v.w) == T) { unsigned i = atomicAdd(&sh_cnt, 1u); if (i < CAPL) cand[i] = fkey(v.w); }
    }
    __syncthreads();
    unsigned k = sh_cnt; if (k > CAPL) k = CAPL;

    // ---- min/max reduce over candidate keys ----
    unsigned lmin = 0xFFFFFFFFu, lmax = 0u;
    for (unsigned j = tid; j < k; j += 1024) { unsigned v = cand[j]; lmin = umn(lmin, v); lmax = umx(lmax, v); }
    #pragma unroll
    for (int o = 1; o < 64; o <<= 1) {
        lmin = umn(lmin, (unsigned)__shfl_xor((int)lmin, o));
        lmax = umx(lmax, (unsigned)__shfl_xor((int)lmax, o));
    }
    if (lane == 0) { redmin[wid] = lmin; redmax[wid] = lmax; }
    if (tid < 512) hsub[tid] = 0;
    __syncthreads();
    if (tid == 0) {
        unsigned mn = redmin[0], mx = redmax[0];
        for (int w = 1; w < 16; ++w) { mn = umn(mn, redmin[w]); mx = umx(mx, redmax[w]); }
        unsigned spread = mx - mn;
        int bits = 32 - __clz((int)(spread | 1u));
        sh_shift = (unsigned)(bits > 9 ? bits - 9 : 0);   // (spread>>shift) < 512
        sh_kmin = mn;
    }
    __syncthreads();
    const unsigned kmin = sh_kmin, shift = sh_shift;
    for (unsigned j = tid; j < k; j += 1024) atomicAdd(&hsub[(cand[j] - kmin) >> shift], 1u);
    __syncthreads();

    // ---- find rank sub-bin over 512 (1 bin/thread, block scan) ----
    unsigned s2 = (tid < 512) ? hsub[tid] : 0u;
    unsigned incl2 = s2;
    #pragma unroll
    for (int o = 1; o < 64; o <<= 1) {
        unsigned v = (unsigned)__shfl_up((int)incl2, o);
        if (lane >= o) incl2 += v;
    }
    if (lane == 63) wsum[wid] = incl2;
    __syncthreads();
    if (tid == 0) { unsigned c = 0; for (int w = 0; w < 16; ++w) { woff[w] = c; c += wsum[w]; } }
    __syncthreads();
    unsigned excl2 = woff[wid] + incl2 - s2;
    if (tid < 512 && s2 && r >= excl2 && r < excl2 + s2) { sh_sb = (unsigned)tid; sh_r2 = r - excl2; }
    __syncthreads();
    const unsigned sb = sh_sb;

    // ---- exact tie-aware rank among bin candidates (test only sub-bin elems) ----
    for (unsigned j = tid; j < k; j += 1024) {
        unsigned v = cand[j];
        if (((v - kmin) >> shift) != sb) continue;
        unsigned less = 0, eq = 0;
        for (unsigned q = 0; q < k; ++q) {
            unsigned u = cand[q];
            less += (u < v);
            eq   += (u == v);
        }
        if (less <= r && r < less + eq) thresh[b] = finv(v);
    }
}

// ---------------- Kernel 4: losses -> selection flags (in place) ----------------
__global__ __launch_bounds__(256) void emit_kernel(
    float* __restrict__ out, const float* __restrict__ thresh,
    const unsigned* __restrict__ present)
{
    int i4 = blockIdx.x * 256 + threadIdx.x;
    int i = i4 * 4;
    int b = i >> 18;
    int p = i & (HW - 1);
    float th = thresh[b];
    unsigned pm = present[b];
    float4 v = reinterpret_cast<float4*>(out)[i4];
    float4 o;
    o.x = ((v.x > th) || ((p + 0) < NC && ((pm >> (p + 0)) & 1u))) ? 1.f : 0.f;
    o.y = ((v.y > th) || ((p + 1) < NC && ((pm >> (p + 1)) & 1u))) ? 1.f : 0.f;
    o.z = ((v.z > th) || ((p + 2) < NC && ((pm >> (p + 2)) & 1u))) ? 1.f : 0.f;
    o.w = ((v.w > th) || ((p + 3) < NC && ((pm >> (p + 3)) & 1u))) ? 1.f : 0.f;
    reinterpret_cast<float4*>(out)[i4] = o;
}

extern "C" void kernel_launch(void* const* d_in, const int* in_sizes, int n_in,
                              void* d_out, int out_size, void* d_ws, size_t ws_size,
                              hipStream_t stream)
{
    const float* logits  = (const float*)d_in[0];
    const int*   targets = (const int*)d_in[1];
    float* out = (float*)d_out;   // doubles as the losses buffer (NPIX floats)

    char* ws = (char*)d_ws;
    unsigned* present = (unsigned*)(ws);        // 8 u32
    float*    thresh  = (float*)   (ws + 32);   // 8 f32
    unsigned* ghist   = (unsigned*)(ws + 64);   // 8*4096 u32 (zeroed in losses_kernel)

    hipMemsetAsync(present, 0, 32, stream);     // only `present` needs pre-zero

    losses_kernel<<<NPIX / 512, 256, 0, stream>>>(logits, targets, out, present, ghist);
    hist_kernel<<<dim3(64, NB), 256, 0, stream>>>(out, ghist);
    select_kernel<<<NB, 1024, 0, stream>>>(out, ghist, thresh);
    emit_kernel<<<NPIX / 4 / 256, 256, 0, stream>>>(out, thresh, present);
}